// Round 2
// baseline (1728.638 us; speedup 1.0000x reference)
//
#include <hip/hip_runtime.h>
#include <cstdint>
#include <cstddef>

#define T_DIM 4096
#define H_DIM 4096
#define I_DIM 11008

typedef int v4i __attribute__((ext_vector_type(4)));

// ---------------------------------------------------------------------------
// async global->LDS copy, 16B per lane (global_load_lds_dwordx4)
// ---------------------------------------------------------------------------
__device__ __forceinline__ void async_copy16(const void* g, void* l) {
  __builtin_amdgcn_global_load_lds(
      (const __attribute__((address_space(1))) void*)g,
      (__attribute__((address_space(3))) void*)l, 16, 0, 0);
}

// Stage a 128x64 int8 tile (row-major, leading dim ld) into LDS.
// LDS layout: row r occupies bytes [r*64, r*64+64), 4 chunks of 16B.
// XOR swizzle: physical chunk p holds logical (k) chunk c = p ^ ((r>>1)&3).
// global_load_lds constraint: LDS dest = wave-uniform base + lane*16, so the
// swizzle is applied to the *global* source address, not the LDS address.
// Issues exactly 2 VMEM ops per lane.
__device__ __forceinline__ void stage_tile(const int8_t* src, size_t ld,
                                           char* ldsbase, int wave, int lane) {
#pragma unroll
  for (int q = 0; q < 2; ++q) {
    int seg = q * 4 + wave;            // 0..7, 16 rows per segment
    int r = seg * 16 + (lane >> 2);    // tile-local row 0..127
    int p = lane & 3;                  // physical 16B chunk
    int c = p ^ ((r >> 1) & 3);        // logical k chunk
    const int8_t* g = src + (size_t)r * ld + (size_t)c * 16;
    char* lp = ldsbase + seg * 1024;   // wave-uniform base; lane writes +lane*16
    async_copy16((const void*)g, (void*)lp);
  }
}

// Load one 16x16x64 i8 MFMA A/B fragment from a swizzled LDS tile.
__device__ __forceinline__ v4i frag_load(const char* ldsbase, int rowbase, int lane) {
  int r = rowbase + (lane & 15);
  int c = (lane >> 4) ^ ((r >> 1) & 3);
  return *(const v4i*)(ldsbase + r * 64 + c * 16);
}

// ---------------------------------------------------------------------------
// int32 -> int8 pack (values already in [-127,127])
// ---------------------------------------------------------------------------
__global__ void pack_i8(const int4* __restrict__ src, char4* __restrict__ dst, int n4) {
  int stride = gridDim.x * blockDim.x;
  for (int i = blockIdx.x * blockDim.x + threadIdx.x; i < n4; i += stride) {
    int4 v = src[i];
    char4 c;
    c.x = (char)v.x; c.y = (char)v.y; c.z = (char)v.z; c.w = (char)v.w;
    dst[i] = c;
  }
}

__global__ void zero_u32(unsigned* __restrict__ p, int n) {
  int i = blockIdx.x * blockDim.x + threadIdx.x;
  if (i < n) p[i] = 0u;
}

// ---------------------------------------------------------------------------
// GEMM1 compute step: 64x64(x2) per wave from one staged K=64 tile.
// ---------------------------------------------------------------------------
__device__ __forceinline__ void g1_step(const char* LA, const char* LBG, const char* LBU,
                                        int wm, int wn, int lane,
                                        v4i (&accg)[4][4], v4i (&accu)[4][4]) {
  v4i a[4], bg[4], bu[4];
#pragma unroll
  for (int i = 0; i < 4; i++) a[i]  = frag_load(LA,  wm * 64 + i * 16, lane);
#pragma unroll
  for (int j = 0; j < 4; j++) bg[j] = frag_load(LBG, wn * 64 + j * 16, lane);
#pragma unroll
  for (int j = 0; j < 4; j++) bu[j] = frag_load(LBU, wn * 64 + j * 16, lane);
#pragma unroll
  for (int i = 0; i < 4; i++)
#pragma unroll
    for (int j = 0; j < 4; j++) {
      accg[i][j] = __builtin_amdgcn_mfma_i32_16x16x64_i8(a[i], bg[j], accg[i][j], 0, 0, 0);
      accu[i][j] = __builtin_amdgcn_mfma_i32_16x16x64_i8(a[i], bu[j], accu[i][j], 0, 0, 0);
    }
}

// ---------------------------------------------------------------------------
// GEMM1 fused: gu = x_q @ w_gate_up^T, epilogue y = silu(gate)*up, fp32 store,
// per-row absmax via shfl-reduce + atomicMax on float bits.
// 128x128 tile, BK=64, 4 waves each computing 64x64(x2).
// Triple-buffered LDS with COUNTED vmcnt (T4): stage for tile t+2 issued in
// phase t; per phase ONE raw s_barrier + s_waitcnt vmcnt(6) (never 0 in the
// main loop) -> every load gets ~2 compute phases of latency slack.
// ---------------------------------------------------------------------------
__global__ __launch_bounds__(256, 2)
void gemm1_silu(const int8_t* __restrict__ x8,
                const int8_t* __restrict__ wgu8,
                const float* __restrict__ x_scale,
                const float* __restrict__ s_wgu,
                float* __restrict__ y,
                unsigned* __restrict__ rowmax) {
  __shared__ __align__(16) char lds0[24576];
  __shared__ __align__(16) char lds1[24576];
  __shared__ __align__(16) char lds2[24576];
  char* Abuf[3]  = {lds0,         lds1,         lds2};
  char* Bgbuf[3] = {lds0 + 8192,  lds1 + 8192,  lds2 + 8192};
  char* Bubuf[3] = {lds0 + 16384, lds1 + 16384, lds2 + 16384};

  const int tid = threadIdx.x;
  const int wave = tid >> 6, lane = tid & 63;
  const int wm = wave >> 1, wn = wave & 1;

  // T1: XCD-aware swizzle. nwg = 86*32 = 2752, %8 == 0 -> bijective.
  const unsigned nwg = gridDim.x * gridDim.y;
  const unsigned bid = blockIdx.y * gridDim.x + blockIdx.x;
  const unsigned cpx = nwg >> 3;
  const unsigned swz = (bid & 7) * cpx + (bid >> 3);
  const int m0 = (int)(swz / gridDim.x) * 128;
  const int n0 = (int)(swz % gridDim.x) * 128;

  v4i accg[4][4], accu[4][4];
  const v4i vzero = {0, 0, 0, 0};
#pragma unroll
  for (int i = 0; i < 4; i++)
#pragma unroll
    for (int j = 0; j < 4; j++) { accg[i][j] = vzero; accu[i][j] = vzero; }

  const int8_t* Ab  = x8 + (size_t)m0 * H_DIM;
  const int8_t* Bgb = wgu8 + (size_t)n0 * H_DIM;
  const int8_t* Bub = wgu8 + ((size_t)I_DIM + (size_t)n0) * H_DIM;

  // prologue: stage tiles 0 and 1 (12 VMEM ops in flight per lane)
  stage_tile(Ab,       H_DIM, Abuf[0],  wave, lane);
  stage_tile(Bgb,      H_DIM, Bgbuf[0], wave, lane);
  stage_tile(Bub,      H_DIM, Bubuf[0], wave, lane);
  stage_tile(Ab + 64,  H_DIM, Abuf[1],  wave, lane);
  stage_tile(Bgb + 64, H_DIM, Bgbuf[1], wave, lane);
  stage_tile(Bub + 64, H_DIM, Bubuf[1], wave, lane);

  // Phase t: wait tile t ready (vmcnt(6) leaves tile t+1's 6 loads in flight),
  // barrier (cross-wave readiness of buf t AND everyone done reading buf
  // (t+2)%3 from compute t-1), stage tile t+2, compute tile t.
#define G1_PHASE(B, T)                                                    \
  {                                                                       \
    asm volatile("s_waitcnt vmcnt(6) lgkmcnt(0)" ::: "memory");           \
    __builtin_amdgcn_s_barrier();                                         \
    __builtin_amdgcn_sched_barrier(0);                                    \
    const int kn_ = ((T) + 2) << 6;                                       \
    if (kn_ < H_DIM) {                                                    \
      stage_tile(Ab + kn_,  H_DIM, Abuf[((B) + 2) % 3],  wave, lane);     \
      stage_tile(Bgb + kn_, H_DIM, Bgbuf[((B) + 2) % 3], wave, lane);     \
      stage_tile(Bub + kn_, H_DIM, Bubuf[((B) + 2) % 3], wave, lane);     \
    }                                                                     \
    g1_step(Abuf[(B)], Bgbuf[(B)], Bubuf[(B)], wm, wn, lane, accg, accu); \
  }

  // 64 K-steps total: 21 groups of 3 cover t = 0..62, then tail t = 63.
  for (int t = 0; t < 63; t += 3) {
    G1_PHASE(0, t)
    G1_PHASE(1, t + 1)
    G1_PHASE(2, t + 2)
  }
  // tail: only tile 63 (buf 0) in flight -> full drain
  asm volatile("s_waitcnt vmcnt(0) lgkmcnt(0)" ::: "memory");
  __builtin_amdgcn_s_barrier();
  __builtin_amdgcn_sched_barrier(0);
  g1_step(Abuf[0], Bgbuf[0], Bubuf[0], wm, wn, lane, accg, accu);
#undef G1_PHASE

  // Epilogue. C/D layout (verified, dtype-independent): col = lane&15,
  // row = (lane>>4)*4 + reg.
  const int lr = lane >> 4;
  const int lc = lane & 15;
#pragma unroll
  for (int i = 0; i < 4; i++) {
#pragma unroll
    for (int t = 0; t < 4; t++) {
      const int gr = m0 + wm * 64 + i * 16 + lr * 4 + t;
      const float sx = x_scale[gr];
      float vmax = 0.f;
#pragma unroll
      for (int j = 0; j < 4; j++) {
        const int gc = n0 + wn * 64 + j * 16 + lc;
        float g = (float)accg[i][j][t] * sx * s_wgu[gc];
        float u = (float)accu[i][j][t] * sx * s_wgu[I_DIM + gc];
        float yv = (g / (1.f + expf(-g))) * u;   // silu(g) * u
        y[(size_t)gr * I_DIM + gc] = yv;
        vmax = fmaxf(vmax, fabsf(yv));
      }
      // reduce max across the 16 lanes sharing this row (lane bits 0..3)
#pragma unroll
      for (int off = 1; off < 16; off <<= 1)
        vmax = fmaxf(vmax, __shfl_xor(vmax, off, 64));
      if (lc == 0) atomicMax(&rowmax[gr], __float_as_uint(vmax));
    }
  }
}

// ---------------------------------------------------------------------------
// quantize y -> int8 with dynamic per-row scale s2 = max(|y|,1e-8)/127
// jnp.round == round-half-even == rintf
// ---------------------------------------------------------------------------
__global__ void quantize_y(const float* __restrict__ y,
                           const unsigned* __restrict__ rowmax,
                           int8_t* __restrict__ yq) {
  size_t gid = (size_t)blockIdx.x * blockDim.x + threadIdx.x;
  size_t base = gid * 4;
  if (base >= (size_t)T_DIM * I_DIM) return;
  int row = (int)(base / I_DIM);   // I_DIM % 4 == 0, packs never cross rows
  float inv = 127.f / fmaxf(__uint_as_float(rowmax[row]), 1e-8f);
  float4 v = *(const float4*)(y + base);
  char4 q;
  q.x = (char)(int)fminf(127.f, fmaxf(-128.f, rintf(v.x * inv)));
  q.y = (char)(int)fminf(127.f, fmaxf(-128.f, rintf(v.y * inv)));
  q.z = (char)(int)fminf(127.f, fmaxf(-128.f, rintf(v.z * inv)));
  q.w = (char)(int)fminf(127.f, fmaxf(-128.f, rintf(v.w * inv)));
  *(char4*)(yq + base) = q;
}

// ---------------------------------------------------------------------------
// GEMM2 compute step
// ---------------------------------------------------------------------------
__device__ __forceinline__ void g2_step(const char* LA, const char* LB,
                                        int wm, int wn, int lane,
                                        v4i (&acc)[4][4]) {
  v4i a[4], b[4];
#pragma unroll
  for (int i = 0; i < 4; i++) a[i] = frag_load(LA, wm * 64 + i * 16, lane);
#pragma unroll
  for (int j = 0; j < 4; j++) b[j] = frag_load(LB, wn * 64 + j * 16, lane);
#pragma unroll
  for (int i = 0; i < 4; i++)
#pragma unroll
    for (int j = 0; j < 4; j++)
      acc[i][j] = __builtin_amdgcn_mfma_i32_16x16x64_i8(a[i], b[j], acc[i][j], 0, 0, 0);
}

// ---------------------------------------------------------------------------
// GEMM2: out = (y_q @ w_down^T) * s2[row] * s_w_down[col]
// Same triple-buffered counted-vmcnt pipeline (S = 4 loads per stage-group).
// ---------------------------------------------------------------------------
__global__ __launch_bounds__(256, 3)
void gemm2_scaled(const int8_t* __restrict__ yq8,
                  const int8_t* __restrict__ wd8,
                  const unsigned* __restrict__ rowmax,
                  const float* __restrict__ s_wd,
                  float* __restrict__ out) {
  __shared__ __align__(16) char lds0[16384];
  __shared__ __align__(16) char lds1[16384];
  __shared__ __align__(16) char lds2[16384];
  char* Abuf[3] = {lds0,        lds1,        lds2};
  char* Bbuf[3] = {lds0 + 8192, lds1 + 8192, lds2 + 8192};

  const int tid = threadIdx.x;
  const int wave = tid >> 6, lane = tid & 63;
  const int wm = wave >> 1, wn = wave & 1;

  // T1 swizzle: nwg = 32*32 = 1024, %8 == 0.
  const unsigned nwg = gridDim.x * gridDim.y;
  const unsigned bid = blockIdx.y * gridDim.x + blockIdx.x;
  const unsigned cpx = nwg >> 3;
  const unsigned swz = (bid & 7) * cpx + (bid >> 3);
  const int m0 = (int)(swz / gridDim.x) * 128;
  const int n0 = (int)(swz % gridDim.x) * 128;

  v4i acc[4][4];
  const v4i vzero = {0, 0, 0, 0};
#pragma unroll
  for (int i = 0; i < 4; i++)
#pragma unroll
    for (int j = 0; j < 4; j++) acc[i][j] = vzero;

  const int8_t* Ab = yq8 + (size_t)m0 * I_DIM;
  const int8_t* Bb = wd8 + (size_t)n0 * I_DIM;

  // prologue: stage tiles 0 and 1 (8 VMEM ops in flight per lane)
  stage_tile(Ab,      I_DIM, Abuf[0], wave, lane);
  stage_tile(Bb,      I_DIM, Bbuf[0], wave, lane);
  stage_tile(Ab + 64, I_DIM, Abuf[1], wave, lane);
  stage_tile(Bb + 64, I_DIM, Bbuf[1], wave, lane);

#define G2_PHASE(B, T)                                                    \
  {                                                                       \
    asm volatile("s_waitcnt vmcnt(4) lgkmcnt(0)" ::: "memory");           \
    __builtin_amdgcn_s_barrier();                                         \
    __builtin_amdgcn_sched_barrier(0);                                    \
    const int kn_ = ((T) + 2) << 6;                                       \
    if (kn_ < I_DIM) {                                                    \
      stage_tile(Ab + kn_, I_DIM, Abuf[((B) + 2) % 3], wave, lane);       \
      stage_tile(Bb + kn_, I_DIM, Bbuf[((B) + 2) % 3], wave, lane);       \
    }                                                                     \
    g2_step(Abuf[(B)], Bbuf[(B)], wm, wn, lane, acc);                     \
  }

  // 172 K-steps: 57 groups of 3 cover t = 0..170, then tail t = 171 (buf 0).
  for (int t = 0; t < 171; t += 3) {
    G2_PHASE(0, t)
    G2_PHASE(1, t + 1)
    G2_PHASE(2, t + 2)
  }
  asm volatile("s_waitcnt vmcnt(0) lgkmcnt(0)" ::: "memory");
  __builtin_amdgcn_s_barrier();
  __builtin_amdgcn_sched_barrier(0);
  g2_step(Abuf[0], Bbuf[0], wm, wn, lane, acc);
#undef G2_PHASE

  const int lr = lane >> 4;
  const int lc = lane & 15;
#pragma unroll
  for (int i = 0; i < 4; i++) {
#pragma unroll
    for (int t = 0; t < 4; t++) {
      const int gr = m0 + wm * 64 + i * 16 + lr * 4 + t;
      const float s2 = fmaxf(__uint_as_float(rowmax[gr]), 1e-8f) / 127.f;
#pragma unroll
      for (int j = 0; j < 4; j++) {
        const int gc = n0 + wn * 64 + j * 16 + lc;
        out[(size_t)gr * H_DIM + gc] = (float)acc[i][j][t] * s2 * s_wd[gc];
      }
    }
  }
}

// ---------------------------------------------------------------------------
// launch
// ---------------------------------------------------------------------------
extern "C" void kernel_launch(void* const* d_in, const int* in_sizes, int n_in,
                              void* d_out, int out_size, void* d_ws, size_t ws_size,
                              hipStream_t stream) {
  const int*   x_q     = (const int*)d_in[0];
  const float* x_scale = (const float*)d_in[1];
  const int*   w_gu    = (const int*)d_in[2];
  const float* s_wgu   = (const float*)d_in[3];
  const int*   w_d     = (const int*)d_in[4];
  const float* s_wd    = (const float*)d_in[5];
  float* out = (float*)d_out;

  // workspace layout (bytes)
  char* ws = (char*)d_ws;
  const size_t SZ_X8   = (size_t)T_DIM * H_DIM;          //  16,777,216
  const size_t SZ_WGU8 = (size_t)2 * I_DIM * H_DIM;      //  90,177,536
  const size_t SZ_WD8  = (size_t)H_DIM * I_DIM;          //  45,088,768
  const size_t SZ_Y    = (size_t)T_DIM * I_DIM * 4;      // 180,355,072
  const size_t SZ_YQ   = (size_t)T_DIM * I_DIM;          //  45,088,768

  int8_t*   x8     = (int8_t*)ws;
  int8_t*   wgu8   = (int8_t*)(ws + SZ_X8);
  int8_t*   wd8    = (int8_t*)(ws + SZ_X8 + SZ_WGU8);
  float*    y      = (float*)(ws + SZ_X8 + SZ_WGU8 + SZ_WD8);
  int8_t*   yq8    = (int8_t*)(ws + SZ_X8 + SZ_WGU8 + SZ_WD8 + SZ_Y);
  unsigned* rowmax = (unsigned*)(ws + SZ_X8 + SZ_WGU8 + SZ_WD8 + SZ_Y + SZ_YQ);

  // 1) pack int32 -> int8
  pack_i8<<<dim3(8192), dim3(256), 0, stream>>>((const int4*)x_q,  (char4*)x8,   (int)(SZ_X8 / 4));
  pack_i8<<<dim3(8192), dim3(256), 0, stream>>>((const int4*)w_gu, (char4*)wgu8, (int)(SZ_WGU8 / 4));
  pack_i8<<<dim3(8192), dim3(256), 0, stream>>>((const int4*)w_d,  (char4*)wd8,  (int)(SZ_WD8 / 4));
  zero_u32<<<dim3(16), dim3(256), 0, stream>>>(rowmax, T_DIM);

  // 2) fused GEMM1 + silu*up + row absmax
  gemm1_silu<<<dim3(I_DIM / 128, T_DIM / 128), dim3(256), 0, stream>>>(
      x8, wgu8, x_scale, s_wgu, y, rowmax);

  // 3) dynamic per-row quantization
  quantize_y<<<dim3((unsigned)((size_t)T_DIM * I_DIM / 4 / 256)), dim3(256), 0, stream>>>(
      y, rowmax, yq8);

  // 4) GEMM2 + scale epilogue
  gemm2_scaled<<<dim3(H_DIM / 128, T_DIM / 128), dim3(256), 0, stream>>>(
      yq8, wd8, rowmax, s_wd, out);
}

// Round 3
// 1342.659 us; speedup vs baseline: 1.2875x; 1.2875x over previous
//
#include <hip/hip_runtime.h>
#include <cstdint>
#include <cstddef>

#define T_DIM 4096
#define H_DIM 4096
#define I_DIM 11008

typedef int v4i __attribute__((ext_vector_type(4)));

// ---------------------------------------------------------------------------
// async global->LDS copy, 16B per lane (global_load_lds_dwordx4)
// ---------------------------------------------------------------------------
__device__ __forceinline__ void async_copy16(const void* g, void* l) {
  __builtin_amdgcn_global_load_lds(
      (const __attribute__((address_space(1))) void*)g,
      (__attribute__((address_space(3))) void*)l, 16, 0, 0);
}

// Stage a 128x64 int8 tile (row-major, leading dim ld) into LDS.
// LDS layout: row r occupies bytes [r*64, r*64+64), 4 chunks of 16B.
// XOR swizzle: physical chunk p holds logical (k) chunk c = p ^ ((r>>1)&3)
// so that ds_read_b128 fragment reads land at 2-way bank conflicts (free).
// global_load_lds constraint: LDS dest = wave-uniform base + lane*16, so the
// swizzle is applied to the *global* source address, not the LDS address.
__device__ __forceinline__ void stage_tile(const int8_t* src, size_t ld,
                                           char* ldsbase, int wave, int lane) {
#pragma unroll
  for (int q = 0; q < 2; ++q) {
    int seg = q * 4 + wave;            // 0..7, 16 rows per segment
    int r = seg * 16 + (lane >> 2);    // tile-local row 0..127
    int p = lane & 3;                  // physical 16B chunk
    int c = p ^ ((r >> 1) & 3);        // logical k chunk
    const int8_t* g = src + (size_t)r * ld + (size_t)c * 16;
    char* lp = ldsbase + seg * 1024;   // wave-uniform base; lane writes +lane*16
    async_copy16((const void*)g, (void*)lp);
  }
}

// Load one 16x16x64 i8 MFMA A/B fragment from a swizzled LDS tile.
__device__ __forceinline__ v4i frag_load(const char* ldsbase, int rowbase, int lane) {
  int r = rowbase + (lane & 15);
  int c = (lane >> 4) ^ ((r >> 1) & 3);
  return *(const v4i*)(ldsbase + r * 64 + c * 16);
}

// ---------------------------------------------------------------------------
// int32 -> int8 pack (values already in [-127,127])
// ---------------------------------------------------------------------------
__global__ void pack_i8(const int4* __restrict__ src, char4* __restrict__ dst, int n4) {
  int stride = gridDim.x * blockDim.x;
  for (int i = blockIdx.x * blockDim.x + threadIdx.x; i < n4; i += stride) {
    int4 v = src[i];
    char4 c;
    c.x = (char)v.x; c.y = (char)v.y; c.z = (char)v.z; c.w = (char)v.w;
    dst[i] = c;
  }
}

__global__ void zero_u32(unsigned* __restrict__ p, int n) {
  int i = blockIdx.x * blockDim.x + threadIdx.x;
  if (i < n) p[i] = 0u;
}

// ---------------------------------------------------------------------------
// GEMM1 compute step: 64x64(x2) per wave from one staged K=64 tile.
// ---------------------------------------------------------------------------
__device__ __forceinline__ void g1_step(const char* LA, const char* LBG, const char* LBU,
                                        int wm, int wn, int lane,
                                        v4i (&accg)[4][4], v4i (&accu)[4][4]) {
  v4i a[4], bg[4], bu[4];
#pragma unroll
  for (int i = 0; i < 4; i++) a[i]  = frag_load(LA,  wm * 64 + i * 16, lane);
#pragma unroll
  for (int j = 0; j < 4; j++) bg[j] = frag_load(LBG, wn * 64 + j * 16, lane);
#pragma unroll
  for (int j = 0; j < 4; j++) bu[j] = frag_load(LBU, wn * 64 + j * 16, lane);
#pragma unroll
  for (int i = 0; i < 4; i++)
#pragma unroll
    for (int j = 0; j < 4; j++) {
      accg[i][j] = __builtin_amdgcn_mfma_i32_16x16x64_i8(a[i], bg[j], accg[i][j], 0, 0, 0);
      accu[i][j] = __builtin_amdgcn_mfma_i32_16x16x64_i8(a[i], bu[j], accu[i][j], 0, 0, 0);
    }
}

// ---------------------------------------------------------------------------
// GEMM1 fused: gu = x_q @ w_gate_up^T (gate cols n and up cols I+n in one
// block sharing the A tile), epilogue y = silu(gate)*up, store y fp32,
// per-row absmax via shfl-reduce + atomicMax on float bits.
// 128x128 tile, BK=64, 4 waves each computing 64x64 (4x4 subtiles of 16x16).
// Double-buffered LDS: prefetch of tile k+1 issued BEFORE compute of tile k;
// one vmcnt(0)-drain + barrier (__syncthreads) per K-step.
// ---------------------------------------------------------------------------
__global__ __launch_bounds__(256, 2)
void gemm1_silu(const int8_t* __restrict__ x8,
                const int8_t* __restrict__ wgu8,
                const float* __restrict__ x_scale,
                const float* __restrict__ s_wgu,
                float* __restrict__ y,
                unsigned* __restrict__ rowmax) {
  // two distinct __shared__ objects -> trivially NoAlias, so the compiler
  // cannot insert a spurious vmcnt wait between prefetch and current ds_reads
  __shared__ __align__(16) char lds0[24576];
  __shared__ __align__(16) char lds1[24576];
  char* A0 = lds0;  char* Bg0 = lds0 + 8192;  char* Bu0 = lds0 + 16384;
  char* A1 = lds1;  char* Bg1 = lds1 + 8192;  char* Bu1 = lds1 + 16384;

  const int tid = threadIdx.x;
  const int wave = tid >> 6, lane = tid & 63;
  const int wm = wave >> 1, wn = wave & 1;

  // Supertile XCD swizzle. Consecutive bids round-robin across 8 XCDs, so
  // (bid&7) selects the XCD-local chunk. Each XCD owns 344 ids = m-rows
  // [xcd*4, xcd*4+4) x all 86 n-cols. Within the chunk, order blocks in
  // 4m x 8n supertiles (32 blocks ~ one XCD's co-residency capacity):
  // co-resident blocks then share 4 A panels (2MB) + 8 Bg/Bu panel pairs
  // (8MB) with short L2 reuse distance, instead of 64 distinct B panels.
  const unsigned bid = blockIdx.y * gridDim.x + blockIdx.x;
  const unsigned xcd = bid & 7;
  const unsigned l   = bid >> 3;        // 0..343
  const unsigned s   = l >> 5;          // supertile 0..10 (last has 6 n-cols)
  const unsigned r   = l - (s << 5);    // 0..31 (0..23 in the last supertile)
  const int m0 = (int)(xcd * 4 + (r & 3)) * 128;
  const int n0 = (int)(s * 8 + (r >> 2)) * 128;

  v4i accg[4][4], accu[4][4];
  const v4i vzero = {0, 0, 0, 0};
#pragma unroll
  for (int i = 0; i < 4; i++)
#pragma unroll
    for (int j = 0; j < 4; j++) { accg[i][j] = vzero; accu[i][j] = vzero; }

  const int8_t* Ab  = x8 + (size_t)m0 * H_DIM;
  const int8_t* Bgb = wgu8 + (size_t)n0 * H_DIM;
  const int8_t* Bub = wgu8 + ((size_t)I_DIM + (size_t)n0) * H_DIM;

  // prologue: stage tile k=0 into buf0
  stage_tile(Ab,  H_DIM, A0,  wave, lane);
  stage_tile(Bgb, H_DIM, Bg0, wave, lane);
  stage_tile(Bub, H_DIM, Bu0, wave, lane);
  __syncthreads();

  // H_DIM/64 = 64 K-steps, unrolled x2 so buffer choice is compile-time static
  for (int k0 = 0; k0 < H_DIM; k0 += 128) {
    {  // phase 0: prefetch k0+64 -> buf1, compute k0 from buf0
      const int kn = k0 + 64;
      if (kn < H_DIM) {
        stage_tile(Ab + kn,  H_DIM, A1,  wave, lane);
        stage_tile(Bgb + kn, H_DIM, Bg1, wave, lane);
        stage_tile(Bub + kn, H_DIM, Bu1, wave, lane);
      }
      g1_step(A0, Bg0, Bu0, wm, wn, lane, accg, accu);
      __syncthreads();   // vmcnt(0)+lgkmcnt(0) drain + barrier: buf1 ready, buf0 free
    }
    {  // phase 1: prefetch k0+128 -> buf0, compute k0+64 from buf1
      const int kn = k0 + 128;
      if (kn < H_DIM) {
        stage_tile(Ab + kn,  H_DIM, A0,  wave, lane);
        stage_tile(Bgb + kn, H_DIM, Bg0, wave, lane);
        stage_tile(Bub + kn, H_DIM, Bu0, wave, lane);
      }
      g1_step(A1, Bg1, Bu1, wm, wn, lane, accg, accu);
      __syncthreads();
    }
  }

  // Epilogue. C/D layout (verified, dtype-independent): col = lane&15,
  // row = (lane>>4)*4 + reg.
  const int lr = lane >> 4;
  const int lc = lane & 15;
#pragma unroll
  for (int i = 0; i < 4; i++) {
#pragma unroll
    for (int t = 0; t < 4; t++) {
      const int gr = m0 + wm * 64 + i * 16 + lr * 4 + t;
      const float sx = x_scale[gr];
      float vmax = 0.f;
#pragma unroll
      for (int j = 0; j < 4; j++) {
        const int gc = n0 + wn * 64 + j * 16 + lc;
        float g = (float)accg[i][j][t] * sx * s_wgu[gc];
        float u = (float)accu[i][j][t] * sx * s_wgu[I_DIM + gc];
        float yv = (g / (1.f + expf(-g))) * u;   // silu(g) * u
        y[(size_t)gr * I_DIM + gc] = yv;
        vmax = fmaxf(vmax, fabsf(yv));
      }
      // reduce max across the 16 lanes sharing this row (lane bits 0..3)
#pragma unroll
      for (int off = 1; off < 16; off <<= 1)
        vmax = fmaxf(vmax, __shfl_xor(vmax, off, 64));
      if (lc == 0) atomicMax(&rowmax[gr], __float_as_uint(vmax));
    }
  }
}

// ---------------------------------------------------------------------------
// quantize y -> int8 with dynamic per-row scale s2 = max(|y|,1e-8)/127
// jnp.round == round-half-even == rintf
// ---------------------------------------------------------------------------
__global__ void quantize_y(const float* __restrict__ y,
                           const unsigned* __restrict__ rowmax,
                           int8_t* __restrict__ yq) {
  size_t gid = (size_t)blockIdx.x * blockDim.x + threadIdx.x;
  size_t base = gid * 4;
  if (base >= (size_t)T_DIM * I_DIM) return;
  int row = (int)(base / I_DIM);   // I_DIM % 4 == 0, packs never cross rows
  float inv = 127.f / fmaxf(__uint_as_float(rowmax[row]), 1e-8f);
  float4 v = *(const float4*)(y + base);
  char4 q;
  q.x = (char)(int)fminf(127.f, fmaxf(-128.f, rintf(v.x * inv)));
  q.y = (char)(int)fminf(127.f, fmaxf(-128.f, rintf(v.y * inv)));
  q.z = (char)(int)fminf(127.f, fmaxf(-128.f, rintf(v.z * inv)));
  q.w = (char)(int)fminf(127.f, fmaxf(-128.f, rintf(v.w * inv)));
  *(char4*)(yq + base) = q;
}

// ---------------------------------------------------------------------------
// GEMM2 compute step
// ---------------------------------------------------------------------------
__device__ __forceinline__ void g2_step(const char* LA, const char* LB,
                                        int wm, int wn, int lane,
                                        v4i (&acc)[4][4]) {
  v4i a[4], b[4];
#pragma unroll
  for (int i = 0; i < 4; i++) a[i] = frag_load(LA, wm * 64 + i * 16, lane);
#pragma unroll
  for (int j = 0; j < 4; j++) b[j] = frag_load(LB, wn * 64 + j * 16, lane);
#pragma unroll
  for (int i = 0; i < 4; i++)
#pragma unroll
    for (int j = 0; j < 4; j++)
      acc[i][j] = __builtin_amdgcn_mfma_i32_16x16x64_i8(a[i], b[j], acc[i][j], 0, 0, 0);
}

// ---------------------------------------------------------------------------
// GEMM2: out = (y_q @ w_down^T) * s2[row] * s_w_down[col]
// Same double-buffered 2-phase pipeline. acc is only 64 regs -> 3 blocks/CU.
// ---------------------------------------------------------------------------
__global__ __launch_bounds__(256, 3)
void gemm2_scaled(const int8_t* __restrict__ yq8,
                  const int8_t* __restrict__ wd8,
                  const unsigned* __restrict__ rowmax,
                  const float* __restrict__ s_wd,
                  float* __restrict__ out) {
  __shared__ __align__(16) char lds0[16384];
  __shared__ __align__(16) char lds1[16384];
  char* A0 = lds0;  char* B0 = lds0 + 8192;
  char* A1 = lds1;  char* B1 = lds1 + 8192;

  const int tid = threadIdx.x;
  const int wave = tid >> 6, lane = tid & 63;
  const int wm = wave >> 1, wn = wave & 1;

  // Supertile XCD swizzle: 1024 blocks, each XCD owns 128 ids = 4 m-rows x
  // 32 n-cols, ordered in 4m x 8n supertiles (exactly 4 per XCD).
  const unsigned bid = blockIdx.y * gridDim.x + blockIdx.x;
  const unsigned xcd = bid & 7;
  const unsigned l   = bid >> 3;        // 0..127
  const unsigned s   = l >> 5;          // 0..3
  const unsigned r   = l & 31;
  const int m0 = (int)(xcd * 4 + (r & 3)) * 128;
  const int n0 = (int)(s * 8 + (r >> 2)) * 128;

  v4i acc[4][4];
  const v4i vzero = {0, 0, 0, 0};
#pragma unroll
  for (int i = 0; i < 4; i++)
#pragma unroll
    for (int j = 0; j < 4; j++) acc[i][j] = vzero;

  const int8_t* Ab = yq8 + (size_t)m0 * I_DIM;
  const int8_t* Bb = wd8 + (size_t)n0 * I_DIM;

  stage_tile(Ab, I_DIM, A0, wave, lane);
  stage_tile(Bb, I_DIM, B0, wave, lane);
  __syncthreads();

  // I_DIM/64 = 172 K-steps (even), unrolled x2
  for (int k0 = 0; k0 < I_DIM; k0 += 128) {
    {
      const int kn = k0 + 64;
      if (kn < I_DIM) {
        stage_tile(Ab + kn, I_DIM, A1, wave, lane);
        stage_tile(Bb + kn, I_DIM, B1, wave, lane);
      }
      g2_step(A0, B0, wm, wn, lane, acc);
      __syncthreads();
    }
    {
      const int kn = k0 + 128;
      if (kn < I_DIM) {
        stage_tile(Ab + kn, I_DIM, A0, wave, lane);
        stage_tile(Bb + kn, I_DIM, B0, wave, lane);
      }
      g2_step(A1, B1, wm, wn, lane, acc);
      __syncthreads();
    }
  }

  const int lr = lane >> 4;
  const int lc = lane & 15;
#pragma unroll
  for (int i = 0; i < 4; i++) {
#pragma unroll
    for (int t = 0; t < 4; t++) {
      const int gr = m0 + wm * 64 + i * 16 + lr * 4 + t;
      const float s2 = fmaxf(__uint_as_float(rowmax[gr]), 1e-8f) / 127.f;
#pragma unroll
      for (int j = 0; j < 4; j++) {
        const int gc = n0 + wn * 64 + j * 16 + lc;
        out[(size_t)gr * H_DIM + gc] = (float)acc[i][j][t] * s2 * s_wd[gc];
      }
    }
  }
}

// ---------------------------------------------------------------------------
// launch
// ---------------------------------------------------------------------------
extern "C" void kernel_launch(void* const* d_in, const int* in_sizes, int n_in,
                              void* d_out, int out_size, void* d_ws, size_t ws_size,
                              hipStream_t stream) {
  const int*   x_q     = (const int*)d_in[0];
  const float* x_scale = (const float*)d_in[1];
  const int*   w_gu    = (const int*)d_in[2];
  const float* s_wgu   = (const float*)d_in[3];
  const int*   w_d     = (const int*)d_in[4];
  const float* s_wd    = (const float*)d_in[5];
  float* out = (float*)d_out;

  // workspace layout (bytes)
  char* ws = (char*)d_ws;
  const size_t SZ_X8   = (size_t)T_DIM * H_DIM;          //  16,777,216
  const size_t SZ_WGU8 = (size_t)2 * I_DIM * H_DIM;      //  90,177,536
  const size_t SZ_WD8  = (size_t)H_DIM * I_DIM;          //  45,088,768
  const size_t SZ_Y    = (size_t)T_DIM * I_DIM * 4;      // 180,355,072
  const size_t SZ_YQ   = (size_t)T_DIM * I_DIM;          //  45,088,768

  int8_t*   x8     = (int8_t*)ws;
  int8_t*   wgu8   = (int8_t*)(ws + SZ_X8);
  int8_t*   wd8    = (int8_t*)(ws + SZ_X8 + SZ_WGU8);
  float*    y      = (float*)(ws + SZ_X8 + SZ_WGU8 + SZ_WD8);
  int8_t*   yq8    = (int8_t*)(ws + SZ_X8 + SZ_WGU8 + SZ_WD8 + SZ_Y);
  unsigned* rowmax = (unsigned*)(ws + SZ_X8 + SZ_WGU8 + SZ_WD8 + SZ_Y + SZ_YQ);

  // 1) pack int32 -> int8
  pack_i8<<<dim3(8192), dim3(256), 0, stream>>>((const int4*)x_q,  (char4*)x8,   (int)(SZ_X8 / 4));
  pack_i8<<<dim3(8192), dim3(256), 0, stream>>>((const int4*)w_gu, (char4*)wgu8, (int)(SZ_WGU8 / 4));
  pack_i8<<<dim3(8192), dim3(256), 0, stream>>>((const int4*)w_d,  (char4*)wd8,  (int)(SZ_WD8 / 4));
  zero_u32<<<dim3(16), dim3(256), 0, stream>>>(rowmax, T_DIM);

  // 2) fused GEMM1 + silu*up + row absmax
  gemm1_silu<<<dim3(I_DIM / 128, T_DIM / 128), dim3(256), 0, stream>>>(
      x8, wgu8, x_scale, s_wgu, y, rowmax);

  // 3) dynamic per-row quantization
  quantize_y<<<dim3((unsigned)((size_t)T_DIM * I_DIM / 4 / 256)), dim3(256), 0, stream>>>(
      y, rowmax, yq8);

  // 4) GEMM2 + scale epilogue
  gemm2_scaled<<<dim3(H_DIM / 128, T_DIM / 128), dim3(256), 0, stream>>>(
      yq8, wd8, rowmax, s_wd, out);
}